// Round 8
// baseline (71.215 us; speedup 1.0000x reference)
//
#include <hip/hip_runtime.h>

#define EPSF 1e-5f
#define SER 4   // series per block in compute kernel; grid = 8192/SER = 2048

typedef float f32x4 __attribute__((ext_vector_type(4)));

// B=8,E=16,N=64 -> 8192 series, T=128, D=32 hidden, OUT=64 output channels.
//   y1[d][t] = relu(a[d] conv x + c1[d])            (BN1 folded, pad=1)
//   y2[t]    = relu(sum_d w2f[d] conv y1[d] + c2)   (BN2 folded, pad=1 on y1!)
//   out[o][t]= w3[o]*y2[t] + b3[o]
// r7 fused = 49.5us (5.4 TB/s). Five fused structures all land 49.5-51.9 ->
// decisive split: kernel A computes y2 (4 MB ws, pure VALU ~5us), kernel B is
// a fill-kernel clone (256 thr, grid-stride, 1 cached 16B load + 4 FMA +
// 1 16B store per iter). Tests whether a load+store kernel can reach the
// demonstrated 7.0 TB/s fill ceiling. o,q are iteration-invariant per thread
// (stride = total threads) -> w3/b3 hoisted to registers.

// ---- Kernel A: y2 for all series -> ws ----
__global__ __launch_bounds__(128) void y2_kernel(
    const float* __restrict__ x_in,   // [S][128]
    const float* __restrict__ w1, const float* __restrict__ b1,
    const float* __restrict__ w2, const float* __restrict__ b2,
    const float* __restrict__ g1, const float* __restrict__ be1,
    const float* __restrict__ m1, const float* __restrict__ v1,
    const float* __restrict__ g2, const float* __restrict__ be2,
    const float* __restrict__ m2, const float* __restrict__ v2,
    float* __restrict__ y2ws)         // [S][128]
{
    __shared__ float x_s[SER][132];   // 2-zero halo both ends
    __shared__ f32x4 pkA_s[32];       // {a0,a1,a2,c1}
    __shared__ f32x4 pkB_s[32];       // {w20,w21,w22,0}
    __shared__ float c2_s;

    const int tid = threadIdx.x;
    const size_t s0 = (size_t)blockIdx.x * SER;

    #pragma unroll
    for (int s = 0; s < SER; ++s)
        x_s[s][2 + tid] = x_in[(s0 + s) * 128 + tid];
    if (tid < SER) {
        x_s[tid][0] = 0.f; x_s[tid][1] = 0.f;
        x_s[tid][130] = 0.f; x_s[tid][131] = 0.f;
    }
    if (tid < 32) {
        const int d = tid;
        float inv = g1[d] * rsqrtf(v1[d] + EPSF);
        f32x4 A;
        A.x = inv * w1[d * 3 + 0];
        A.y = inv * w1[d * 3 + 1];
        A.z = inv * w1[d * 3 + 2];
        A.w = b1[d] * inv + be1[d] - m1[d] * inv;
        pkA_s[d] = A;
    } else if (tid < 64) {
        const int d = tid - 32;
        float s2 = g2[0] * rsqrtf(v2[0] + EPSF);
        f32x4 W;
        W.x = s2 * w2[d * 3 + 0];
        W.y = s2 * w2[d * 3 + 1];
        W.z = s2 * w2[d * 3 + 2];
        W.w = 0.f;
        pkB_s[d] = W;
        if (d == 0) c2_s = b2[0] * s2 + be2[0] - m2[0] * s2;
    }
    __syncthreads();

    const float mm = (tid == 0)   ? 0.f : 1.f;   // y1[d][-1] conv2-pad
    const float mp = (tid == 127) ? 0.f : 1.f;   // y1[d][128] conv2-pad
    const float c2 = c2_s;

    #pragma unroll
    for (int s = 0; s < SER; ++s) {
        const float xm2 = x_s[s][tid];
        const float xm1 = x_s[s][tid + 1];
        const float x0  = x_s[s][tid + 2];
        const float xp1 = x_s[s][tid + 3];
        const float xp2 = x_s[s][tid + 4];

        float accm = 0.f, acc0 = 0.f, accp = 0.f;
        #pragma unroll 4
        for (int d = 0; d < 32; ++d) {
            const f32x4 A = pkA_s[d];
            const f32x4 W = pkB_s[d];
            float ym = fmaxf(fmaf(A.x, xm2, fmaf(A.y, xm1, fmaf(A.z, x0,  A.w))), 0.f);
            float y0 = fmaxf(fmaf(A.x, xm1, fmaf(A.y, x0,  fmaf(A.z, xp1, A.w))), 0.f);
            float yp = fmaxf(fmaf(A.x, x0,  fmaf(A.y, xp1, fmaf(A.z, xp2, A.w))), 0.f);
            accm = fmaf(W.x, ym, accm);
            acc0 = fmaf(W.y, y0, acc0);
            accp = fmaf(W.z, yp, accp);
        }
        y2ws[(s0 + s) * 128 + tid] =
            fmaxf(fmaf(mm, accm, fmaf(mp, accp, acc0 + c2)), 0.f);
    }
}

// ---- Kernel B: fill-clone expand/store ----
// quad index f = ((s*64 + o)*32 + q); threads stride by gridDim*256 so
// o = (f>>5)&63 and q = f&31 are per-thread constants; only s advances.
__global__ __launch_bounds__(256) void expand_kernel(
    const float* __restrict__ y2ws,   // [S][128]
    const float* __restrict__ w3,     // [64]
    const float* __restrict__ b3,     // [64]
    float* __restrict__ out,          // [S][64][128]
    int n_iters)                      // quads per thread
{
    const int f0 = blockIdx.x * 256 + threadIdx.x;
    const int o  = (f0 >> 5) & 63;
    const int q  = f0 & 31;
    const float w = w3[o];
    const float b = b3[o];
    const int stride = gridDim.x * 256;           // in quads
    const int s_step = stride >> 11;              // series advance per iter

    const f32x4* ysrc = (const f32x4*)(y2ws + (size_t)(f0 >> 11) * 128) + q;
    f32x4* dst = (f32x4*)out + f0;

    #pragma unroll 4
    for (int it = 0; it < n_iters; ++it) {
        const f32x4 y = ysrc[(size_t)it * s_step * 32];
        f32x4 r;
        r.x = fmaf(w, y.x, b);
        r.y = fmaf(w, y.y, b);
        r.z = fmaf(w, y.z, b);
        r.w = fmaf(w, y.w, b);
        dst[(size_t)it * stride] = r;
    }
}

extern "C" void kernel_launch(void* const* d_in, const int* in_sizes, int n_in,
                              void* d_out, int out_size, void* d_ws, size_t ws_size,
                              hipStream_t stream) {
    const float* x   = (const float*)d_in[0];   // node_features
    // d_in[1] edge_features: unused by the reference computation
    const float* w1  = (const float*)d_in[2];
    const float* b1  = (const float*)d_in[3];
    const float* w2  = (const float*)d_in[4];
    const float* b2  = (const float*)d_in[5];
    const float* w3  = (const float*)d_in[6];
    const float* b3  = (const float*)d_in[7];
    const float* g1  = (const float*)d_in[8];
    const float* be1 = (const float*)d_in[9];
    const float* m1  = (const float*)d_in[10];
    const float* v1  = (const float*)d_in[11];
    const float* g2  = (const float*)d_in[12];
    const float* be2 = (const float*)d_in[13];
    const float* m2  = (const float*)d_in[14];
    const float* v2  = (const float*)d_in[15];

    const int T = 128;
    const int n_series = in_sizes[0] / T;       // 8192
    float* y2ws = (float*)d_ws;                 // 4 MB

    y2_kernel<<<n_series / SER, 128, 0, stream>>>(
        x, w1, b1, w2, b2, g1, be1, m1, v1, g2, be2, m2, v2, y2ws);

    const int n_quads  = n_series * 64 * 128 / 4;   // 16,777,216
    const int n_blocks = 2048;
    const int n_iters  = n_quads / (n_blocks * 256); // 32
    expand_kernel<<<n_blocks, 256, 0, stream>>>(y2ws, w3, b3, (float*)d_out,
                                                n_iters);
}

// Round 9
// 48.210 us; speedup vs baseline: 1.4772x; 1.4772x over previous
//
#include <hip/hip_runtime.h>

#define EPSF 1e-5f
#define SER 4   // series per block; grid = 8192/SER = 2048

typedef float f32x4 __attribute__((ext_vector_type(4)));

// B=8,E=16,N=64 -> 8192 series, T=128, D=32 hidden, OUT=64 output channels.
//   y1[d][t] = relu(a[d] conv x + c1[d])            (BN1 folded, pad=1)
//   y2[t]    = relu(sum_d w2f[d] conv y1[d] + c2)   (BN2 folded, pad=1 on y1!)
//   out[o][t]= w3[o]*y2[t] + b3[o]
// Write-BW-bound: 256 MiB out; fill ceiling ~6.9 TB/s -> ~39 us floor.
// r7 fused/no-barrier = 49.5us @ 16 waves/CU. r8 split = 71us (64x read
// amplification -> fused zero-global-read structure is right).
// r9 lever: OCCUPANCY. 256-thread blocks, launch_bounds(256,8) -> 32 waves/CU
// (vs 16), w3/b3 from LDS broadcasts (not 32 VGPRs) to stay under 64 VGPR.
// Each inner step processes a series PAIR: threads tid>>7 pick the series,
// two waves per series, wave-local shfl exchange, no barriers after prologue.

__global__ __launch_bounds__(256, 8) void hnc_kernel(
    const float* __restrict__ x_in,   // [S][128]
    const float* __restrict__ w1,     // [32][1][3]
    const float* __restrict__ b1,     // [32]
    const float* __restrict__ w2,     // [1][32][3]
    const float* __restrict__ b2,     // [1]
    const float* __restrict__ w3,     // [64]
    const float* __restrict__ b3,     // [64]
    const float* __restrict__ g1, const float* __restrict__ be1,
    const float* __restrict__ m1, const float* __restrict__ v1,
    const float* __restrict__ g2, const float* __restrict__ be2,
    const float* __restrict__ m2, const float* __restrict__ v2,
    float* __restrict__ out)          // [S][64][128]
{
    __shared__ float x_s[SER][132];   // 2-zero halo both ends (read-only after prologue)
    __shared__ f32x4 pkA_s[32];       // {a0,a1,a2,c1}  (BN1-folded conv1)
    __shared__ f32x4 pkB_s[32];       // {w20,w21,w22,0} (BN2-folded conv2)
    __shared__ float w3_s[64];
    __shared__ float b3_s[64];
    __shared__ float c2_s;

    const int tid  = threadIdx.x;     // 0..255
    const int tt   = tid & 127;       // y2 position this thread computes
    const int sp   = tid >> 7;        // series-within-pair (0/1)
    const int lane = tid & 63;
    const size_t s0 = (size_t)blockIdx.x * SER;

    // ---- Prologue: stage 4 series' x + fold params; the ONLY barrier ----
    #pragma unroll
    for (int i = 0; i < SER / 2; ++i)
        x_s[2 * i + sp][2 + tt] = x_in[(s0 + 2 * i + sp) * 128 + tt];
    if (tid < SER) {
        x_s[tid][0] = 0.f; x_s[tid][1] = 0.f;
        x_s[tid][130] = 0.f; x_s[tid][131] = 0.f;
    }
    if (tid < 32) {
        const int d = tid;
        float inv = g1[d] * rsqrtf(v1[d] + EPSF);
        f32x4 A;
        A.x = inv * w1[d * 3 + 0];
        A.y = inv * w1[d * 3 + 1];
        A.z = inv * w1[d * 3 + 2];
        A.w = b1[d] * inv + be1[d] - m1[d] * inv;
        pkA_s[d] = A;
    } else if (tid < 64) {
        const int d = tid - 32;
        float s2 = g2[0] * rsqrtf(v2[0] + EPSF);
        f32x4 W;
        W.x = s2 * w2[d * 3 + 0];
        W.y = s2 * w2[d * 3 + 1];
        W.z = s2 * w2[d * 3 + 2];
        W.w = 0.f;
        pkB_s[d] = W;
        if (d == 0) c2_s = b2[0] * s2 + be2[0] - m2[0] * s2;
    } else if (tid < 128) {
        const int o = tid - 64;
        w3_s[o] = w3[o];
        b3_s[o] = b3[o];
    }
    __syncthreads();

    const int g    = lane >> 4;                    // o-residue mod 4
    const int qq   = (tt >> 6) * 16 + (lane & 15); // quad index this thread stores
    const int srcl = 4 * (lane & 15);              // shfl source base (wave-local)
    const float mm = (tt == 0)   ? 0.f : 1.f;      // y1[d][-1] conv2-pad
    const float mp = (tt == 127) ? 0.f : 1.f;      // y1[d][128] conv2-pad
    const float c2 = c2_s;

    // ---- Pipelined pair loop: NO barriers, stores never drained ----
    #pragma unroll
    for (int u = 0; u < SER / 2; ++u) {
        const int s = 2 * u + sp;
        const float xm2 = x_s[s][tt];
        const float xm1 = x_s[s][tt + 1];
        const float x0  = x_s[s][tt + 2];
        const float xp1 = x_s[s][tt + 3];
        const float xp2 = x_s[s][tt + 4];

        float accm = 0.f, acc0 = 0.f, accp = 0.f;
        #pragma unroll 4
        for (int d = 0; d < 32; ++d) {
            const f32x4 A = pkA_s[d];
            const f32x4 W = pkB_s[d];
            float ym = fmaxf(fmaf(A.x, xm2, fmaf(A.y, xm1, fmaf(A.z, x0,  A.w))), 0.f);
            float y0 = fmaxf(fmaf(A.x, xm1, fmaf(A.y, x0,  fmaf(A.z, xp1, A.w))), 0.f);
            float yp = fmaxf(fmaf(A.x, x0,  fmaf(A.y, xp1, fmaf(A.z, xp2, A.w))), 0.f);
            accm = fmaf(W.x, ym, accm);
            acc0 = fmaf(W.y, y0, acc0);
            accp = fmaf(W.z, yp, accp);
        }
        const float y2v = fmaxf(fmaf(mm, accm, fmaf(mp, accp, acc0 + c2)), 0.f);

        // wave-local y2 exchange: this thread's stored quad [4qq..4qq+3]
        f32x4 y;
        y.x = __shfl(y2v, srcl + 0, 64);
        y.y = __shfl(y2v, srcl + 1, 64);
        y.z = __shfl(y2v, srcl + 2, 64);
        y.w = __shfl(y2v, srcl + 3, 64);

        // 16 coalesced f32x4 stores; w3/b3 are LDS broadcast reads
        f32x4* out4 = (f32x4*)(out + (s0 + s) * 64 * 128);
        #pragma unroll
        for (int i = 0; i < 16; ++i) {
            const int o = 4 * i + g;
            const float w = w3_s[o], b = b3_s[o];
            f32x4 r;
            r.x = fmaf(w, y.x, b);
            r.y = fmaf(w, y.y, b);
            r.z = fmaf(w, y.z, b);
            r.w = fmaf(w, y.w, b);
            out4[o * 32 + qq] = r;
        }
    }
}

extern "C" void kernel_launch(void* const* d_in, const int* in_sizes, int n_in,
                              void* d_out, int out_size, void* d_ws, size_t ws_size,
                              hipStream_t stream) {
    const float* x   = (const float*)d_in[0];   // node_features [B,E,N,T,1]
    // d_in[1] edge_features: unused by the reference computation
    const float* w1  = (const float*)d_in[2];
    const float* b1  = (const float*)d_in[3];
    const float* w2  = (const float*)d_in[4];
    const float* b2  = (const float*)d_in[5];
    const float* w3  = (const float*)d_in[6];
    const float* b3  = (const float*)d_in[7];
    const float* g1  = (const float*)d_in[8];
    const float* be1 = (const float*)d_in[9];
    const float* m1  = (const float*)d_in[10];
    const float* v1  = (const float*)d_in[11];
    const float* g2  = (const float*)d_in[12];
    const float* be2 = (const float*)d_in[13];
    const float* m2  = (const float*)d_in[14];
    const float* v2  = (const float*)d_in[15];

    const int T = 128;
    const int n_series = in_sizes[0] / T;       // 8192
    const int n_blocks = n_series / SER;        // 2048

    hnc_kernel<<<n_blocks, 256, 0, stream>>>(x, w1, b1, w2, b2, w3, b3,
                                             g1, be1, m1, v1, g2, be2, m2, v2,
                                             (float*)d_out);
}